// Round 4
// baseline (804.447 us; speedup 1.0000x reference)
//
#include <hip/hip_runtime.h>

#define WS7    7
#define SHIFT3 3
#define NHEAD  6
#define CCH    192
#define HDIM   32
#define HH56   56
#define LTOK   (HH56*HH56)      // 3136
#define NWIN   64
#define NBATCH 32
#define NWTOT  (NBATCH*NWIN)    // 2048
#define LW     49
#define MTOK   (NWTOT*LW)       // 100352

typedef unsigned short u16;
typedef unsigned int   u32;
typedef __bf16 b16;
typedef b16   b16x8 __attribute__((ext_vector_type(8)));
typedef u16   u16x8 __attribute__((ext_vector_type(8)));
typedef float f32x4 __attribute__((ext_vector_type(4)));

__device__ __forceinline__ float b2f(u16 u) {
    u32 x = ((u32)u) << 16;
    return __builtin_bit_cast(float, x);
}
__device__ __forceinline__ u16 f2b(float f) {
    u32 x = __builtin_bit_cast(u32, f);
    u32 r = x + 0x7FFFu + ((x >> 16) & 1u);
    return (u16)(r >> 16);
}
__device__ __forceinline__ float gelu_exact(float x) {
    return 0.5f * x * (1.0f + erff(x * 0.7071067811865475f));
}

// token m (window-order) -> (b, l) image order (bijection)
__device__ __forceinline__ int map_token(int m, int &b) {
    int widx = m / LW, p = m - widx * LW;
    b = widx >> 6;
    int wloc = widx & 63;
    int wh = wloc >> 3, ww = wloc & 7;
    int i = p / WS7, j = p - i * WS7;
    int gh = wh * WS7 + i + SHIFT3; if (gh >= HH56) gh -= HH56;
    int gw = ww * WS7 + j + SHIFT3; if (gw >= HH56) gw -= HH56;
    return gh * HH56 + gw;
}

// ---- dtype probe: flag=1 if x is fp32 storage, 0 if bf16 storage.
__global__ __launch_bounds__(1024) void probe_kernel(const u16* __restrict__ x, int* flag) {
    __shared__ int ch, cz;
    if (threadIdx.x == 0) { ch = 0; cz = 0; }
    __syncthreads();
    int i = threadIdx.x * 16;
    u16x8 a = *(const u16x8*)(x + i);
    u16x8 b = *(const u16x8*)(x + i + 8);
    int h = 0, z = 0;
    #pragma unroll
    for (int q = 0; q < 8; q++) {
        h += (((a[q] >> 7) & 0xFF) >= 0xC0) + (((b[q] >> 7) & 0xFF) >= 0xC0);
        z += (a[q] == 0) + (b[q] == 0);
    }
    #pragma unroll
    for (int off = 32; off > 0; off >>= 1) {
        h += __shfl_xor(h, off, 64);
        z += __shfl_xor(z, off, 64);
    }
    if ((threadIdx.x & 63) == 0) { atomicAdd(&ch, h); atomicAdd(&cz, z); }
    __syncthreads();
    if (threadIdx.x == 0) *flag = (ch > 250 || cz > 2048) ? 1 : 0;
}

// ---- canonicalize ALL param tensors to bf16 in ONE launch.
#define CANON_TOTAL 445302
__global__ __launch_bounds__(256) void canon_all_kernel(
    const int* __restrict__ flag,
    const void* s0, const void* s1, const void* s2,  const void* s3,
    const void* s4, const void* s5, const void* s6,  const void* s7,
    const void* s8, const void* s9, const void* s10, const void* s11,
    char* __restrict__ ws)
{
    int i = blockIdx.x * 256 + threadIdx.x;
    if (i >= CANON_TOTAL) return;
    const void* srcs[12] = {s0, s1, s2, s3, s4, s5, s6, s7, s8, s9, s10, s11};
    const int cnt[12] = {110592, 36864, 147456, 147456, 192, 192, 192, 192, 192, 768, 192, 1014};
    const int off[12] = {64, 221248, 294976, 589888, 884800, 885184, 885568, 885952, 886336, 886720, 888256, 888640};
    int seg = 0, base = 0;
    while (seg < 11 && i >= base + cnt[seg]) { base += cnt[seg]; seg++; }
    int j = i - base;
    const void* sp = srcs[seg];
    u16* dp = (u16*)(ws + off[seg]);
    dp[j] = (*flag) ? f2b(((const float*)sp)[j]) : ((const u16*)sp)[j];
}

// ---- LayerNorm (gather variant; LN2 is fused into FC1).
template<int GATHER>
__global__ __launch_bounds__(256) void ln_kernel(
    const void* __restrict__ src, const u16* __restrict__ w, const u16* __restrict__ bia,
    u16* __restrict__ dst, int m_base, const int* __restrict__ flag)
{
    int wave = threadIdx.x >> 6, lane = threadIdx.x & 63;
    int mloc = blockIdx.x * 4 + wave;
    size_t row;
    if (GATHER) { int b; int l = map_token(m_base + mloc, b); row = (size_t)b * LTOK + l; }
    else row = mloc;
    float v0, v1, v2;
    if (GATHER && *flag) {
        const float* xp = (const float*)src + row * CCH;
        v0 = xp[lane]; v1 = xp[lane + 64]; v2 = xp[lane + 128];
    } else {
        const u16* xp = (const u16*)src + row * CCH;
        v0 = b2f(xp[lane]); v1 = b2f(xp[lane + 64]); v2 = b2f(xp[lane + 128]);
    }
    float s = v0 + v1 + v2, sq = v0 * v0 + v1 * v1 + v2 * v2;
    for (int off = 32; off > 0; off >>= 1) {
        s  += __shfl_xor(s, off, 64);
        sq += __shfl_xor(sq, off, 64);
    }
    float mean = s * (1.f / 192.f);
    float var  = fmaxf(sq * (1.f / 192.f) - mean * mean, 0.f);
    float rstd = rsqrtf(var + 1e-5f);
    u16* op = dst + (size_t)mloc * CCH;
    op[lane]       = f2b((v0 - mean) * rstd * b2f(w[lane])       + b2f(bia[lane]));
    op[lane + 64]  = f2b((v1 - mean) * rstd * b2f(w[lane + 64])  + b2f(bia[lane + 64]));
    op[lane + 128] = f2b((v2 - mean) * rstd * b2f(w[lane + 128]) + b2f(bia[lane + 128]));
}

// ---- DMA-stage a 64-row x 192-col bf16 tile into padded LDS [64][200].
__device__ __forceinline__ void stage192(const u16* __restrict__ g, int ldg, u16* s, int tid) {
    #pragma unroll
    for (int it = 0; it < 7; it++) {
        int t = it * 256 + tid;
        if (t < 1600) {                     // 64 rows * 25 chunks
            int row = t / 25, c = t - row * 25;
            int cc = (c == 24) ? 0 : c;
            const u16* src = g + (size_t)row * ldg + cc * 8;
            u16* dst = s + (size_t)(it * 256 + (tid & ~63)) * 8;   // wave base
            __builtin_amdgcn_global_load_lds(
                (const __attribute__((address_space(1))) void*)src,
                (__attribute__((address_space(3))) void*)dst, 16, 0, 0);
        }
    }
}

// ---- in-LDS LayerNorm of the staged 64x192 A tile (rows padded to 200).
__device__ __forceinline__ void ln_lds_rows(u16* As, const u16* __restrict__ w,
                                            const u16* __restrict__ bia, int tid) {
    int r = tid >> 2, p = tid & 3;
    u16* row = As + r * 200 + p * 48;
    u16x8 vv[6];
    float s = 0.f, sq = 0.f;
    #pragma unroll
    for (int j = 0; j < 6; j++) {
        vv[j] = *(const u16x8*)(row + j * 8);
        #pragma unroll
        for (int q = 0; q < 8; q++) { float f = b2f(vv[j][q]); s += f; sq += f * f; }
    }
    s  += __shfl_xor(s, 1, 64);  s  += __shfl_xor(s, 2, 64);
    sq += __shfl_xor(sq, 1, 64); sq += __shfl_xor(sq, 2, 64);
    float mean = s * (1.f / 192.f);
    float var  = fmaxf(sq * (1.f / 192.f) - mean * mean, 0.f);
    float rstd = rsqrtf(var + 1e-5f);
    #pragma unroll
    for (int j = 0; j < 6; j++) {
        u16x8 o;
        #pragma unroll
        for (int q = 0; q < 8; q++) {
            int col = p * 48 + j * 8 + q;
            o[q] = f2b((b2f(vv[j][q]) - mean) * rstd * b2f(w[col]) + b2f(bia[col]));
        }
        *(u16x8*)(row + j * 8) = o;
    }
}

// ---- Universal GEMM: block = 64 rows x 192 cols of C. A (activations) in
// double-buffered LDS (51.2KB -> 3 blocks/CU); B (weights, L2-resident) loaded
// DIRECTLY global->VGPR as MFMA fragments, software-pipelined one k-slice
// ahead. No B staging, no B barriers; 1 barrier per 192-K chunk, and every
// chunk's A-DMA is issued a full compute phase before its drain.
// Wave tile 32x96: 12 MFMA per 2 ds_read_b128.
// MODE 0: C=A*B^T (qkv). MODE 1: proj + residual scatter into X1.
// MODE 2: fc1 + gelu (LNF=1: LayerNorm staged A in LDS first).
// MODE 3: fc2 + gelu + residual(X1) -> Oout.
template<int MODE, int LNF>
__global__ __launch_bounds__(256) void gemm_bd(
    const u16* __restrict__ A, const u16* __restrict__ Bm, int K, int N,
    const u16* __restrict__ lnw, const u16* __restrict__ lnb,
    const u16* __restrict__ bias,
    u16* __restrict__ Cb, u16* __restrict__ X1, const void* __restrict__ Xin,
    void* __restrict__ Oout, size_t o_off, int m_base,
    const int* __restrict__ flag)
{
    __shared__ __align__(16) u16 As[2][64 * 200];
    int isf = *flag;
    int tid = threadIdx.x;
    int m0 = blockIdx.x * 64;
    int n0 = blockIdx.y * 192;
    int wave = tid >> 6, lane = tid & 63;
    int wm = wave >> 1, wn = wave & 1;
    int quad = lane >> 4, mr = lane & 15;

    stage192(A + (size_t)m0 * K, K, As[0], tid);
    __syncthreads();
    if (LNF) { ln_lds_rows(As[0], lnw, lnb, tid); __syncthreads(); }

    f32x4 acc[2][6] = {};
    int nchunks = K / 192;

    #pragma unroll 1
    for (int c = 0; c < nchunks; c++) {
        if (c) __syncthreads();             // drain stage(c) DMA; protect buffers
        if (c + 1 < nchunks)
            stage192(A + (size_t)m0 * K + (c + 1) * 192, K, As[(c + 1) & 1], tid);
        const u16* pa = &As[c & 1][(wm * 32 + mr) * 200 + quad * 8];
        const u16* gb = Bm + (size_t)(n0 + wn * 96 + mr) * K + (size_t)c * 192 + quad * 8;
        u16x8 bf[6];
        #pragma unroll
        for (int sn = 0; sn < 6; sn++) bf[sn] = *(const u16x8*)(gb + (size_t)sn * 16 * K);
        #pragma unroll
        for (int ks = 0; ks < 6; ks++) {
            b16x8 a0 = __builtin_bit_cast(b16x8, *(const u16x8*)(pa + ks * 32));
            b16x8 a1 = __builtin_bit_cast(b16x8, *(const u16x8*)(pa + 16 * 200 + ks * 32));
            u16x8 bcur[6];
            #pragma unroll
            for (int sn = 0; sn < 6; sn++) bcur[sn] = bf[sn];
            if (ks < 5) {
                #pragma unroll
                for (int sn = 0; sn < 6; sn++)
                    bf[sn] = *(const u16x8*)(gb + (size_t)sn * 16 * K + (ks + 1) * 32);
            }
            #pragma unroll
            for (int sn = 0; sn < 6; sn++) {
                b16x8 bb = __builtin_bit_cast(b16x8, bcur[sn]);
                acc[0][sn] = __builtin_amdgcn_mfma_f32_16x16x32_bf16(a0, bb, acc[0][sn], 0, 0, 0);
                acc[1][sn] = __builtin_amdgcn_mfma_f32_16x16x32_bf16(a1, bb, acc[1][sn], 0, 0, 0);
            }
        }
    }

    #pragma unroll
    for (int sm = 0; sm < 2; sm++) {
        #pragma unroll
        for (int sn = 0; sn < 6; sn++) {
            f32x4 v = acc[sm][sn];
            int nn = n0 + wn * 96 + sn * 16 + mr;
            int mb = m0 + wm * 32 + sm * 16 + quad * 4;
            #pragma unroll
            for (int r = 0; r < 4; r++) {
                int mm = mb + r;
                float val = v[r];
                if (MODE == 0) {
                    Cb[(size_t)mm * N + nn] = f2b(val);
                } else if (MODE == 1) {
                    val += b2f(bias[nn]);
                    int b; int l = map_token(m_base + mm, b);
                    size_t idx = ((size_t)b * LTOK + l) * CCH + nn;
                    float xi = isf ? ((const float*)Xin)[idx] : b2f(((const u16*)Xin)[idx]);
                    X1[idx] = f2b(xi + val);
                } else if (MODE == 2) {
                    val = gelu_exact(val + b2f(bias[nn]));
                    Cb[(size_t)mm * N + nn] = f2b(val);
                } else {
                    val = gelu_exact(val + b2f(bias[nn]));
                    size_t idx = (size_t)mm * CCH + nn;
                    float r2 = val + b2f(X1[idx]);
                    if (isf) ((float*)Oout)[o_off + idx] = r2;
                    else     ((u16*)Oout)[o_off + idx]  = f2b(r2);
                }
            }
        }
    }
}

// ---- MFMA attention (unchanged, verified)
__global__ __launch_bounds__(256) void attn_kernel(
    const u16* __restrict__ qkv, const u16* __restrict__ rel_bias,
    u16* __restrict__ aout)
{
    __shared__ __align__(16) u16 qs[64 * 32];
    __shared__ __align__(16) u16 ks[64 * 32];
    __shared__ __align__(16) u16 vsT[32 * 72];
    __shared__ __align__(16) u16 ps[64 * 72];
    __shared__ float bias_s[169];
    int blk = blockIdx.x;
    int widx = blk / NHEAD, head = blk - widx * NHEAD;
    int wloc = widx & 63;
    int wh = wloc >> 3, ww = wloc & 7;
    int tid = threadIdx.x;
    const u16* base = qkv + (size_t)widx * LW * 576 + head * HDIM;

    if (tid < 196) {
        int i = tid >> 2, c8 = (tid & 3) * 8;
        *(uint4*)&qs[i * 32 + c8] = *(const uint4*)(base + (size_t)i * 576 + c8);
        *(uint4*)&ks[i * 32 + c8] = *(const uint4*)(base + (size_t)i * 576 + 192 + c8);
        u16x8 vv = *(const u16x8*)(base + (size_t)i * 576 + 384 + c8);
        #pragma unroll
        for (int q = 0; q < 8; q++) vsT[(c8 + q) * 72 + i] = vv[q];
    }
    for (int idx = tid; idx < 32 * 15; idx += 256) {   // zero pad cols 49..63
        int d = idx / 15, j = 49 + (idx - d * 15);
        vsT[d * 72 + j] = 0;
    }
    if (tid < 169) bias_s[tid] = b2f(rel_bias[tid * NHEAD + head]);
    __syncthreads();

    int wave = tid >> 6, lane = tid & 63;
    int quad = lane >> 4, c = lane & 15;

    b16x8 aq = __builtin_bit_cast(b16x8, *(const u16x8*)&qs[(wave * 16 + c) * 32 + quad * 8]);
    f32x4 sacc[4];
    #pragma unroll
    for (int nt = 0; nt < 4; nt++) {
        b16x8 bk = __builtin_bit_cast(b16x8, *(const u16x8*)&ks[(nt * 16 + c) * 32 + quad * 8]);
        f32x4 z = {};
        sacc[nt] = __builtin_amdgcn_mfma_f32_16x16x32_bf16(aq, bk, z, 0, 0, 0);
    }

    const float SCALE = 13.856406460551018f;
    float val[4][4];
    int rbase = wave * 16 + quad * 4;
    #pragma unroll
    for (int r = 0; r < 4; r++) {
        int i = rbase + r;
        int ih = i / WS7, iw = i - ih * WS7;
        int ri = (wh == 7 ? (ih < 4 ? 1 : 2) : 0) * 3 + (ww == 7 ? (iw < 4 ? 1 : 2) : 0);
        #pragma unroll
        for (int nt = 0; nt < 4; nt++) {
            int j = nt * 16 + c;
            float v;
            if (i >= LW) v = 0.f;
            else if (j >= LW) v = -1e30f;
            else {
                int jh = j / WS7, jw = j - jh * WS7;
                int rj = (wh == 7 ? (jh < 4 ? 1 : 2) : 0) * 3 + (ww == 7 ? (jw < 4 ? 1 : 2) : 0);
                if (ri != rj) v = -100.0f;
                else v = fmaf(sacc[nt][r], SCALE, bias_s[(ih - jh + 6) * 13 + (iw - jw + 6)]);
            }
            val[r][nt] = v;
        }
    }

    #pragma unroll
    for (int r = 0; r < 4; r++) {
        float mx = fmaxf(fmaxf(val[r][0], val[r][1]), fmaxf(val[r][2], val[r][3]));
        for (int d = 1; d < 16; d <<= 1) mx = fmaxf(mx, __shfl_xor(mx, d, 64));
        float sum = 0.f;
        #pragma unroll
        for (int nt = 0; nt < 4; nt++) { float e = expf(val[r][nt] - mx); val[r][nt] = e; sum += e; }
        for (int d = 1; d < 16; d <<= 1) sum += __shfl_xor(sum, d, 64);
        float inv = 1.f / sum;
        int i = rbase + r;
        #pragma unroll
        for (int nt = 0; nt < 4; nt++)
            ps[i * 72 + nt * 16 + c] = f2b(val[r][nt] * inv);
    }

    f32x4 oacc[2] = {{}, {}};
    #pragma unroll
    for (int kh = 0; kh < 2; kh++) {
        b16x8 ap = __builtin_bit_cast(b16x8, *(const u16x8*)&ps[(wave * 16 + c) * 72 + kh * 32 + quad * 8]);
        #pragma unroll
        for (int nt = 0; nt < 2; nt++) {
            b16x8 bv = __builtin_bit_cast(b16x8, *(const u16x8*)&vsT[(nt * 16 + c) * 72 + kh * 32 + quad * 8]);
            oacc[nt] = __builtin_amdgcn_mfma_f32_16x16x32_bf16(ap, bv, oacc[nt], 0, 0, 0);
        }
    }
    #pragma unroll
    for (int nt = 0; nt < 2; nt++) {
        #pragma unroll
        for (int r = 0; r < 4; r++) {
            int i = rbase + r;
            if (i < LW)
                aout[((size_t)widx * LW + i) * CCH + head * HDIM + nt * 16 + c] = f2b(oacc[nt][r]);
        }
    }
}

extern "C" void kernel_launch(void* const* d_in, const int* in_sizes, int n_in,
                              void* d_out, int out_size, void* d_ws, size_t ws_size,
                              hipStream_t stream)
{
    const void* x_in = d_in[0];
    char* ws = (char*)d_ws;
    int* flag = (int*)ws;

    u16* qkvw_c  = (u16*)(ws + 64);
    u16* projw_c = (u16*)(ws + 221248);
    u16* fc1w_c  = (u16*)(ws + 294976);
    u16* fc2w_c  = (u16*)(ws + 589888);
    u16* n1w_c   = (u16*)(ws + 884800);
    u16* n1b_c   = (u16*)(ws + 885184);
    u16* n2w_c   = (u16*)(ws + 885568);
    u16* n2b_c   = (u16*)(ws + 885952);
    u16* projb_c = (u16*)(ws + 886336);
    u16* fc1b_c  = (u16*)(ws + 886720);
    u16* fc2b_c  = (u16*)(ws + 888256);
    u16* relb_c  = (u16*)(ws + 888640);

    const size_t P0 = 1u << 20;
    const size_t X1SZ   = (size_t)MTOK * CCH * 2;   //  38,535,168
    const size_t QKVSZ  = (size_t)MTOK * 576 * 2;   // 115,605,504
    const size_t H1FULL = (size_t)MTOK * 768 * 2;   // 154,140,672

    u16* x1 = (u16*)(ws + P0);

    probe_kernel<<<1, 1024, 0, stream>>>((const u16*)x_in, flag);
    canon_all_kernel<<<(CANON_TOTAL + 255) / 256, 256, 0, stream>>>(
        flag,
        d_in[7], d_in[9], d_in[13], d_in[15],
        d_in[5], d_in[6], d_in[11], d_in[12],
        d_in[10], d_in[14], d_in[16], d_in[8],
        ws);

    // ---- workspace tiering: prefer un-chunked pipeline if ws is big enough.
    int QC, EC;
    u16 *winq, *qkvq, *h1q;
    if (ws_size >= P0 + 2 * X1SZ + H1FULL) {            // 232.3 MB
        QC = 1; EC = 1;
        winq = (u16*)(ws + P0 + X1SZ);
        qkvq = (u16*)(ws + P0 + 2 * X1SZ);
        h1q  = qkvq;                                    // alias: qkvq dead in MLP phase
    } else if (ws_size >= P0 + 2 * X1SZ + QKVSZ) {      // 193.7 MB
        QC = 1; EC = 2;
        winq = (u16*)(ws + P0 + X1SZ);
        qkvq = (u16*)(ws + P0 + 2 * X1SZ);
        h1q  = qkvq;
    } else {                                            // proven 78.1 MB layout
        QC = 4; EC = 8;
        winq = (u16*)(ws + P0 + X1SZ);
        qkvq = (u16*)(ws + P0 + X1SZ + 9633792);
        h1q  = (u16*)(ws + P0 + X1SZ);
    }

    const int MQ = MTOK / QC;
    const int ME = MTOK / EC;

    for (int q = 0; q < QC; q++) {
        int mb = q * MQ;
        ln_kernel<1><<<MQ / 4, 256, 0, stream>>>(x_in, n1w_c, n1b_c, winq, mb, flag);
        gemm_bd<0, 0><<<dim3(MQ / 64, 3), 256, 0, stream>>>(
            winq, qkvw_c, 192, 576, nullptr, nullptr, nullptr,
            qkvq, nullptr, nullptr, nullptr, 0, 0, flag);
        attn_kernel<<<(NWTOT / QC) * NHEAD, 256, 0, stream>>>(qkvq, relb_c, winq);
        gemm_bd<1, 0><<<dim3(MQ / 64, 1), 256, 0, stream>>>(
            winq, projw_c, 192, 192, nullptr, nullptr, projb_c,
            nullptr, x1, x_in, nullptr, 0, mb, flag);
    }

    for (int e = 0; e < EC; e++) {
        size_t off = (size_t)e * ME * CCH;
        gemm_bd<2, 1><<<dim3(ME / 64, 4), 256, 0, stream>>>(
            x1 + off, fc1w_c, 192, 768, n2w_c, n2b_c, fc1b_c,
            h1q, nullptr, nullptr, nullptr, 0, 0, flag);
        gemm_bd<3, 0><<<dim3(ME / 64, 1), 256, 0, stream>>>(
            h1q, fc2w_c, 768, 192, nullptr, nullptr, fc2b_c,
            nullptr, x1 + off, nullptr, d_out, off, 0, flag);
    }
}

// Round 5
// 709.568 us; speedup vs baseline: 1.1337x; 1.1337x over previous
//
#include <hip/hip_runtime.h>

#define WS7    7
#define SHIFT3 3
#define NHEAD  6
#define CCH    192
#define HDIM   32
#define HH56   56
#define LTOK   (HH56*HH56)      // 3136
#define NWIN   64
#define NBATCH 32
#define NWTOT  (NBATCH*NWIN)    // 2048
#define LW     49
#define MTOK   (NWTOT*LW)       // 100352

typedef unsigned short u16;
typedef unsigned int   u32;
typedef __bf16 b16;
typedef b16   b16x8 __attribute__((ext_vector_type(8)));
typedef u16   u16x8 __attribute__((ext_vector_type(8)));
typedef float f32x4 __attribute__((ext_vector_type(4)));

__device__ __forceinline__ float b2f(u16 u) {
    u32 x = ((u32)u) << 16;
    return __builtin_bit_cast(float, x);
}
__device__ __forceinline__ u16 f2b(float f) {
    u32 x = __builtin_bit_cast(u32, f);
    u32 r = x + 0x7FFFu + ((x >> 16) & 1u);
    return (u16)(r >> 16);
}
__device__ __forceinline__ float gelu_exact(float x) {
    return 0.5f * x * (1.0f + erff(x * 0.7071067811865475f));
}

// token m (window-order) -> (b, l) image order (bijection)
__device__ __forceinline__ int map_token(int m, int &b) {
    int widx = m / LW, p = m - widx * LW;
    b = widx >> 6;
    int wloc = widx & 63;
    int wh = wloc >> 3, ww = wloc & 7;
    int i = p / WS7, j = p - i * WS7;
    int gh = wh * WS7 + i + SHIFT3; if (gh >= HH56) gh -= HH56;
    int gw = ww * WS7 + j + SHIFT3; if (gw >= HH56) gw -= HH56;
    return gh * HH56 + gw;
}

// ---- dtype probe: flag=1 if x is fp32 storage, 0 if bf16 storage.
__global__ __launch_bounds__(1024) void probe_kernel(const u16* __restrict__ x, int* flag) {
    __shared__ int ch, cz;
    if (threadIdx.x == 0) { ch = 0; cz = 0; }
    __syncthreads();
    int i = threadIdx.x * 16;
    u16x8 a = *(const u16x8*)(x + i);
    u16x8 b = *(const u16x8*)(x + i + 8);
    int h = 0, z = 0;
    #pragma unroll
    for (int q = 0; q < 8; q++) {
        h += (((a[q] >> 7) & 0xFF) >= 0xC0) + (((b[q] >> 7) & 0xFF) >= 0xC0);
        z += (a[q] == 0) + (b[q] == 0);
    }
    #pragma unroll
    for (int off = 32; off > 0; off >>= 1) {
        h += __shfl_xor(h, off, 64);
        z += __shfl_xor(z, off, 64);
    }
    if ((threadIdx.x & 63) == 0) { atomicAdd(&ch, h); atomicAdd(&cz, z); }
    __syncthreads();
    if (threadIdx.x == 0) *flag = (ch > 250 || cz > 2048) ? 1 : 0;
}

// ---- canonicalize ALL param tensors to bf16 in ONE launch.
#define CANON_TOTAL 445302
__global__ __launch_bounds__(256) void canon_all_kernel(
    const int* __restrict__ flag,
    const void* s0, const void* s1, const void* s2,  const void* s3,
    const void* s4, const void* s5, const void* s6,  const void* s7,
    const void* s8, const void* s9, const void* s10, const void* s11,
    char* __restrict__ ws)
{
    int i = blockIdx.x * 256 + threadIdx.x;
    if (i >= CANON_TOTAL) return;
    const void* srcs[12] = {s0, s1, s2, s3, s4, s5, s6, s7, s8, s9, s10, s11};
    const int cnt[12] = {110592, 36864, 147456, 147456, 192, 192, 192, 192, 192, 768, 192, 1014};
    const int off[12] = {64, 221248, 294976, 589888, 884800, 885184, 885568, 885952, 886336, 886720, 888256, 888640};
    int seg = 0, base = 0;
    while (seg < 11 && i >= base + cnt[seg]) { base += cnt[seg]; seg++; }
    int j = i - base;
    const void* sp = srcs[seg];
    u16* dp = (u16*)(ws + off[seg]);
    dp[j] = (*flag) ? f2b(((const float*)sp)[j]) : ((const u16*)sp)[j];
}

// ---- DMA-stage a 64-row x 192-col bf16 tile into padded LDS [64][200].
__device__ __forceinline__ void stage192(const u16* __restrict__ g, int ldg, u16* s, int tid) {
    #pragma unroll
    for (int it = 0; it < 7; it++) {
        int t = it * 256 + tid;
        if (t < 1600) {                     // 64 rows * 25 chunks
            int row = t / 25, c = t - row * 25;
            int cc = (c == 24) ? 0 : c;
            const u16* src = g + (size_t)row * ldg + cc * 8;
            u16* dst = s + (size_t)(it * 256 + (tid & ~63)) * 8;   // wave base
            __builtin_amdgcn_global_load_lds(
                (const __attribute__((address_space(1))) void*)src,
                (__attribute__((address_space(3))) void*)dst, 16, 0, 0);
        }
    }
}

// ---- in-register LayerNorm of a wave's A fragments (2 rows/lane x 192 cols).
// Lanes sharing mr (the 4 quads) hold the complementary column chunks; reduce
// over lane bits 4-5 via shfl_xor(16/32).
__device__ __forceinline__ void ln_frags(u16x8 af[2][6], const u16* __restrict__ lnw,
                                         const u16* __restrict__ lnb, int quad) {
    float s0 = 0, q0 = 0, s1 = 0, q1 = 0;
    #pragma unroll
    for (int ks = 0; ks < 6; ks++)
        #pragma unroll
        for (int e = 0; e < 8; e++) {
            float f = b2f(af[0][ks][e]); s0 += f; q0 += f * f;
            float g = b2f(af[1][ks][e]); s1 += g; q1 += g * g;
        }
    s0 += __shfl_xor(s0, 16, 64); s0 += __shfl_xor(s0, 32, 64);
    q0 += __shfl_xor(q0, 16, 64); q0 += __shfl_xor(q0, 32, 64);
    s1 += __shfl_xor(s1, 16, 64); s1 += __shfl_xor(s1, 32, 64);
    q1 += __shfl_xor(q1, 16, 64); q1 += __shfl_xor(q1, 32, 64);
    float m0 = s0 * (1.f / 192.f), m1 = s1 * (1.f / 192.f);
    float r0 = rsqrtf(fmaxf(q0 * (1.f / 192.f) - m0 * m0, 0.f) + 1e-5f);
    float r1 = rsqrtf(fmaxf(q1 * (1.f / 192.f) - m1 * m1, 0.f) + 1e-5f);
    #pragma unroll
    for (int ks = 0; ks < 6; ks++) {
        u16x8 wv = *(const u16x8*)(lnw + ks * 32 + quad * 8);
        u16x8 bv = *(const u16x8*)(lnb + ks * 32 + quad * 8);
        #pragma unroll
        for (int e = 0; e < 8; e++) {
            af[0][ks][e] = f2b((b2f(af[0][ks][e]) - m0) * r0 * b2f(wv[e]) + b2f(bv[e]));
            af[1][ks][e] = f2b((b2f(af[1][ks][e]) - m1) * r1 * b2f(wv[e]) + b2f(bv[e]));
        }
    }
}

// ---- Universal GEMM, A-in-registers variant.
// Block = 64 M-rows x full N (n-tiles of 64 looped). LDS = B double-buffer ONLY
// (51.2 KB -> 3 blocks/CU). A fragments live in VGPRs (48), loaded straight
// from global (once for K=192; per k-chunk, L1-hot, for K=768). B tiles are
// DMA-staged exactly one tile ahead; one __syncthreads per tile; epilogue runs
// AFTER the barrier so its stores overlap the next tile's stage+compute.
// MODE 0: qkv  = (gather rows of x via map_token) + LN1 + GEMM      (NT=9)
// MODE 1: proj + bias + residual-scatter into X1                     (NT=3)
// MODE 2: fc1  = LN2(x1 rows) + GEMM + bias + gelu -> h1             (NT=12)
// MODE 3: fc2  (K=768, NC=4) + bias + gelu + residual(X1) -> Oout    (NT=3)
template<int MODE, int NC, int NT>
__global__ __launch_bounds__(256, 4) void gemm_rv(
    const void* __restrict__ Av, const u16* __restrict__ Bm,
    const u16* __restrict__ lnw, const u16* __restrict__ lnb,
    const u16* __restrict__ bias,
    u16* __restrict__ Cb, u16* __restrict__ X1, const void* __restrict__ Xin,
    void* __restrict__ Oout, size_t o_off, int m_base,
    const int* __restrict__ flag)
{
    const int K = NC * 192;
    const int N = NT * 64;
    __shared__ __align__(16) u16 Bs[2][64 * 200];
    int isf = *flag;
    int tid = threadIdx.x;
    int m0 = blockIdx.x * 64;
    int wave = tid >> 6, lane = tid & 63;
    int wm = wave >> 1, wn = wave & 1;
    int quad = lane >> 4, mr = lane & 15;

    stage192(Bm, K, Bs[0], tid);        // B tile 0 DMA overlaps A prologue

    int mrow[2];
    #pragma unroll
    for (int sm = 0; sm < 2; sm++) mrow[sm] = m0 + wm * 32 + sm * 16 + mr;

    u16x8 af[2][6];
    if (MODE == 0) {
        size_t grow[2];
        #pragma unroll
        for (int sm = 0; sm < 2; sm++) {
            int b; int l = map_token(m_base + mrow[sm], b);
            grow[sm] = ((size_t)b * LTOK + l) * CCH;
        }
        if (isf) {
            const float* xf = (const float*)Av;
            float s0 = 0, q0 = 0, s1 = 0, q1 = 0;
            #pragma unroll
            for (int ks = 0; ks < 6; ks++) {
                const float* p0 = xf + grow[0] + ks * 32 + quad * 8;
                const float* p1 = xf + grow[1] + ks * 32 + quad * 8;
                #pragma unroll
                for (int e = 0; e < 8; e++) {
                    float f = p0[e]; s0 += f; q0 += f * f;
                    float g = p1[e]; s1 += g; q1 += g * g;
                }
            }
            s0 += __shfl_xor(s0, 16, 64); s0 += __shfl_xor(s0, 32, 64);
            q0 += __shfl_xor(q0, 16, 64); q0 += __shfl_xor(q0, 32, 64);
            s1 += __shfl_xor(s1, 16, 64); s1 += __shfl_xor(s1, 32, 64);
            q1 += __shfl_xor(q1, 16, 64); q1 += __shfl_xor(q1, 32, 64);
            float mm0 = s0 * (1.f / 192.f), mm1 = s1 * (1.f / 192.f);
            float r0 = rsqrtf(fmaxf(q0 * (1.f / 192.f) - mm0 * mm0, 0.f) + 1e-5f);
            float r1 = rsqrtf(fmaxf(q1 * (1.f / 192.f) - mm1 * mm1, 0.f) + 1e-5f);
            #pragma unroll
            for (int ks = 0; ks < 6; ks++) {
                u16x8 wv = *(const u16x8*)(lnw + ks * 32 + quad * 8);
                u16x8 bv = *(const u16x8*)(lnb + ks * 32 + quad * 8);
                const float* p0 = xf + grow[0] + ks * 32 + quad * 8;
                const float* p1 = xf + grow[1] + ks * 32 + quad * 8;
                #pragma unroll
                for (int e = 0; e < 8; e++) {
                    af[0][ks][e] = f2b((p0[e] - mm0) * r0 * b2f(wv[e]) + b2f(bv[e]));
                    af[1][ks][e] = f2b((p1[e] - mm1) * r1 * b2f(wv[e]) + b2f(bv[e]));
                }
            }
        } else {
            const u16* xb = (const u16*)Av;
            #pragma unroll
            for (int sm = 0; sm < 2; sm++)
                #pragma unroll
                for (int ks = 0; ks < 6; ks++)
                    af[sm][ks] = *(const u16x8*)(xb + grow[sm] + ks * 32 + quad * 8);
            ln_frags(af, lnw, lnb, quad);
        }
    } else if (MODE == 2) {
        const u16* xb = (const u16*)Av;
        #pragma unroll
        for (int sm = 0; sm < 2; sm++)
            #pragma unroll
            for (int ks = 0; ks < 6; ks++)
                af[sm][ks] = *(const u16x8*)(xb + (size_t)mrow[sm] * 192 + ks * 32 + quad * 8);
        ln_frags(af, lnw, lnb, quad);
    } else if (MODE == 1) {
        const u16* xb = (const u16*)Av;
        #pragma unroll
        for (int sm = 0; sm < 2; sm++)
            #pragma unroll
            for (int ks = 0; ks < 6; ks++)
                af[sm][ks] = *(const u16x8*)(xb + (size_t)mrow[sm] * 192 + ks * 32 + quad * 8);
    }

    f32x4 acc[2][2];
    __syncthreads();                    // drain B0 DMA

    #pragma unroll 1
    for (int nb = 0; nb < NT; nb++) {
        #pragma unroll 1
        for (int c = 0; c < NC; c++) {
            int t = nb * NC + c;
            if (t + 1 < NC * NT) {
                int t1 = t + 1, nb1 = t1 / NC, c1 = t1 - nb1 * NC;
                stage192(Bm + (size_t)(nb1 * 64) * K + c1 * 192, K, Bs[t1 & 1], tid);
            }
            if (NC > 1) {               // fc2: A chunk frags (L1-hot after nb=0)
                const u16* xb = (const u16*)Av;
                #pragma unroll
                for (int sm = 0; sm < 2; sm++)
                    #pragma unroll
                    for (int ks = 0; ks < 6; ks++)
                        af[sm][ks] = *(const u16x8*)(xb + (size_t)mrow[sm] * K + c * 192 + ks * 32 + quad * 8);
            }
            if (c == 0) { acc[0][0] = {}; acc[0][1] = {}; acc[1][0] = {}; acc[1][1] = {}; }
            const u16* pb = &Bs[t & 1][(wn * 32 + mr) * 200 + quad * 8];
            #pragma unroll
            for (int ks = 0; ks < 6; ks++) {
                b16x8 b0 = __builtin_bit_cast(b16x8, *(const u16x8*)(pb + ks * 32));
                b16x8 b1 = __builtin_bit_cast(b16x8, *(const u16x8*)(pb + 16 * 200 + ks * 32));
                b16x8 a0 = __builtin_bit_cast(b16x8, af[0][ks]);
                b16x8 a1 = __builtin_bit_cast(b16x8, af[1][ks]);
                acc[0][0] = __builtin_amdgcn_mfma_f32_16x16x32_bf16(a0, b0, acc[0][0], 0, 0, 0);
                acc[0][1] = __builtin_amdgcn_mfma_f32_16x16x32_bf16(a0, b1, acc[0][1], 0, 0, 0);
                acc[1][0] = __builtin_amdgcn_mfma_f32_16x16x32_bf16(a1, b0, acc[1][0], 0, 0, 0);
                acc[1][1] = __builtin_amdgcn_mfma_f32_16x16x32_bf16(a1, b1, acc[1][1], 0, 0, 0);
            }
            __syncthreads();            // drain stage(t+1); protect buffers
            if (c == NC - 1) {          // epilogue AFTER barrier: stores overlap next tile
                #pragma unroll
                for (int sm = 0; sm < 2; sm++)
                    #pragma unroll
                    for (int sn = 0; sn < 2; sn++) {
                        f32x4 v = acc[sm][sn];
                        int nn = nb * 64 + wn * 32 + sn * 16 + mr;
                        int mb2 = m0 + wm * 32 + sm * 16 + quad * 4;
                        #pragma unroll
                        for (int r = 0; r < 4; r++) {
                            int mm = mb2 + r;
                            float val = v[r];
                            if (MODE == 0) {
                                Cb[(size_t)mm * N + nn] = f2b(val);
                            } else if (MODE == 1) {
                                val += b2f(bias[nn]);
                                int b; int l = map_token(m_base + mm, b);
                                size_t idx = ((size_t)b * LTOK + l) * CCH + nn;
                                float xi = isf ? ((const float*)Xin)[idx] : b2f(((const u16*)Xin)[idx]);
                                X1[idx] = f2b(xi + val);
                            } else if (MODE == 2) {
                                val = gelu_exact(val + b2f(bias[nn]));
                                Cb[(size_t)mm * N + nn] = f2b(val);
                            } else {
                                val = gelu_exact(val + b2f(bias[nn]));
                                size_t idx = (size_t)mm * CCH + nn;
                                float r2 = val + b2f(X1[idx]);
                                if (isf) ((float*)Oout)[o_off + idx] = r2;
                                else     ((u16*)Oout)[o_off + idx]  = f2b(r2);
                            }
                        }
                    }
            }
        }
    }
}

// ---- MFMA attention (unchanged, verified)
__global__ __launch_bounds__(256) void attn_kernel(
    const u16* __restrict__ qkv, const u16* __restrict__ rel_bias,
    u16* __restrict__ aout)
{
    __shared__ __align__(16) u16 qs[64 * 32];
    __shared__ __align__(16) u16 ks[64 * 32];
    __shared__ __align__(16) u16 vsT[32 * 72];
    __shared__ __align__(16) u16 ps[64 * 72];
    __shared__ float bias_s[169];
    int blk = blockIdx.x;
    int widx = blk / NHEAD, head = blk - widx * NHEAD;
    int wloc = widx & 63;
    int wh = wloc >> 3, ww = wloc & 7;
    int tid = threadIdx.x;
    const u16* base = qkv + (size_t)widx * LW * 576 + head * HDIM;

    if (tid < 196) {
        int i = tid >> 2, c8 = (tid & 3) * 8;
        *(uint4*)&qs[i * 32 + c8] = *(const uint4*)(base + (size_t)i * 576 + c8);
        *(uint4*)&ks[i * 32 + c8] = *(const uint4*)(base + (size_t)i * 576 + 192 + c8);
        u16x8 vv = *(const u16x8*)(base + (size_t)i * 576 + 384 + c8);
        #pragma unroll
        for (int q = 0; q < 8; q++) vsT[(c8 + q) * 72 + i] = vv[q];
    }
    for (int idx = tid; idx < 32 * 15; idx += 256) {   // zero pad cols 49..63
        int d = idx / 15, j = 49 + (idx - d * 15);
        vsT[d * 72 + j] = 0;
    }
    if (tid < 169) bias_s[tid] = b2f(rel_bias[tid * NHEAD + head]);
    __syncthreads();

    int wave = tid >> 6, lane = tid & 63;
    int quad = lane >> 4, c = lane & 15;

    b16x8 aq = __builtin_bit_cast(b16x8, *(const u16x8*)&qs[(wave * 16 + c) * 32 + quad * 8]);
    f32x4 sacc[4];
    #pragma unroll
    for (int nt = 0; nt < 4; nt++) {
        b16x8 bk = __builtin_bit_cast(b16x8, *(const u16x8*)&ks[(nt * 16 + c) * 32 + quad * 8]);
        f32x4 z = {};
        sacc[nt] = __builtin_amdgcn_mfma_f32_16x16x32_bf16(aq, bk, z, 0, 0, 0);
    }

    const float SCALE = 13.856406460551018f;
    float val[4][4];
    int rbase = wave * 16 + quad * 4;
    #pragma unroll
    for (int r = 0; r < 4; r++) {
        int i = rbase + r;
        int ih = i / WS7, iw = i - ih * WS7;
        int ri = (wh == 7 ? (ih < 4 ? 1 : 2) : 0) * 3 + (ww == 7 ? (iw < 4 ? 1 : 2) : 0);
        #pragma unroll
        for (int nt = 0; nt < 4; nt++) {
            int j = nt * 16 + c;
            float v;
            if (i >= LW) v = 0.f;
            else if (j >= LW) v = -1e30f;
            else {
                int jh = j / WS7, jw = j - jh * WS7;
                int rj = (wh == 7 ? (jh < 4 ? 1 : 2) : 0) * 3 + (ww == 7 ? (jw < 4 ? 1 : 2) : 0);
                if (ri != rj) v = -100.0f;
                else v = fmaf(sacc[nt][r], SCALE, bias_s[(ih - jh + 6) * 13 + (iw - jw + 6)]);
            }
            val[r][nt] = v;
        }
    }

    #pragma unroll
    for (int r = 0; r < 4; r++) {
        float mx = fmaxf(fmaxf(val[r][0], val[r][1]), fmaxf(val[r][2], val[r][3]));
        for (int d = 1; d < 16; d <<= 1) mx = fmaxf(mx, __shfl_xor(mx, d, 64));
        float sum = 0.f;
        #pragma unroll
        for (int nt = 0; nt < 4; nt++) { float e = expf(val[r][nt] - mx); val[r][nt] = e; sum += e; }
        for (int d = 1; d < 16; d <<= 1) sum += __shfl_xor(sum, d, 64);
        float inv = 1.f / sum;
        int i = rbase + r;
        #pragma unroll
        for (int nt = 0; nt < 4; nt++)
            ps[i * 72 + nt * 16 + c] = f2b(val[r][nt] * inv);
    }

    f32x4 oacc[2] = {{}, {}};
    #pragma unroll
    for (int kh = 0; kh < 2; kh++) {
        b16x8 ap = __builtin_bit_cast(b16x8, *(const u16x8*)&ps[(wave * 16 + c) * 72 + kh * 32 + quad * 8]);
        #pragma unroll
        for (int nt = 0; nt < 2; nt++) {
            b16x8 bv = __builtin_bit_cast(b16x8, *(const u16x8*)&vsT[(nt * 16 + c) * 72 + kh * 32 + quad * 8]);
            oacc[nt] = __builtin_amdgcn_mfma_f32_16x16x32_bf16(ap, bv, oacc[nt], 0, 0, 0);
        }
    }
    #pragma unroll
    for (int nt = 0; nt < 2; nt++) {
        #pragma unroll
        for (int r = 0; r < 4; r++) {
            int i = rbase + r;
            if (i < LW)
                aout[((size_t)widx * LW + i) * CCH + head * HDIM + nt * 16 + c] = f2b(oacc[nt][r]);
        }
    }
}

extern "C" void kernel_launch(void* const* d_in, const int* in_sizes, int n_in,
                              void* d_out, int out_size, void* d_ws, size_t ws_size,
                              hipStream_t stream)
{
    const void* x_in = d_in[0];
    char* ws = (char*)d_ws;
    int* flag = (int*)ws;

    u16* qkvw_c  = (u16*)(ws + 64);
    u16* projw_c = (u16*)(ws + 221248);
    u16* fc1w_c  = (u16*)(ws + 294976);
    u16* fc2w_c  = (u16*)(ws + 589888);
    u16* n1w_c   = (u16*)(ws + 884800);
    u16* n1b_c   = (u16*)(ws + 885184);
    u16* n2w_c   = (u16*)(ws + 885568);
    u16* n2b_c   = (u16*)(ws + 885952);
    u16* projb_c = (u16*)(ws + 886336);
    u16* fc1b_c  = (u16*)(ws + 886720);
    u16* fc2b_c  = (u16*)(ws + 888256);
    u16* relb_c  = (u16*)(ws + 888640);

    const size_t P0 = 1u << 20;
    const size_t X1SZ   = (size_t)MTOK * CCH * 2;   //  38,535,168
    const size_t QKVSZ  = (size_t)MTOK * 576 * 2;   // 115,605,504

    u16* x1 = (u16*)(ws + P0);

    probe_kernel<<<1, 1024, 0, stream>>>((const u16*)x_in, flag);
    canon_all_kernel<<<(CANON_TOTAL + 255) / 256, 256, 0, stream>>>(
        flag,
        d_in[7], d_in[9], d_in[13], d_in[15],
        d_in[5], d_in[6], d_in[11], d_in[12],
        d_in[10], d_in[14], d_in[16], d_in[8],
        ws);

    if (ws_size >= P0 + 2 * X1SZ + QKVSZ) {
        // ---- big tier: un-chunked. Layout: x1 | aout | qkvq ; h1 aliases aout+qkvq.
        u16* aout = (u16*)(ws + P0 + X1SZ);
        u16* qkvq = (u16*)(ws + P0 + 2 * X1SZ);
        u16* h1q  = aout;   // 154.1 MB = aout(38.5) + qkvq(115.6), both dead by fc1

        gemm_rv<0, 1, 9><<<MTOK / 64, 256, 0, stream>>>(
            x_in, qkvw_c, n1w_c, n1b_c, nullptr,
            qkvq, nullptr, nullptr, nullptr, 0, 0, flag);
        attn_kernel<<<NWTOT * NHEAD, 256, 0, stream>>>(qkvq, relb_c, aout);
        gemm_rv<1, 1, 3><<<MTOK / 64, 256, 0, stream>>>(
            aout, projw_c, nullptr, nullptr, projb_c,
            nullptr, x1, x_in, nullptr, 0, 0, flag);
        gemm_rv<2, 1, 12><<<MTOK / 64, 256, 0, stream>>>(
            x1, fc1w_c, n2w_c, n2b_c, fc1b_c,
            h1q, nullptr, nullptr, nullptr, 0, 0, flag);
        gemm_rv<3, 4, 3><<<MTOK / 64, 256, 0, stream>>>(
            h1q, fc2w_c, nullptr, nullptr, fc2b_c,
            nullptr, x1, nullptr, d_out, 0, 0, flag);
    } else {
        // ---- small tier (78 MB): 4-way attention phase, 8-way MLP phase.
        const int QC = 4, EC = 8;
        const int MQ = MTOK / QC, ME = MTOK / EC;
        u16* aout_q = (u16*)(ws + P0 + X1SZ);
        u16* qkvq_q = (u16*)(ws + P0 + X1SZ + 9633792);
        u16* h1q    = (u16*)(ws + P0 + X1SZ);

        for (int q = 0; q < QC; q++) {
            int mb = q * MQ;
            gemm_rv<0, 1, 9><<<MQ / 64, 256, 0, stream>>>(
                x_in, qkvw_c, n1w_c, n1b_c, nullptr,
                qkvq_q, nullptr, nullptr, nullptr, 0, mb, flag);
            attn_kernel<<<(NWTOT / QC) * NHEAD, 256, 0, stream>>>(qkvq_q, relb_c, aout_q);
            gemm_rv<1, 1, 3><<<MQ / 64, 256, 0, stream>>>(
                aout_q, projw_c, nullptr, nullptr, projb_c,
                nullptr, x1, x_in, nullptr, 0, mb, flag);
        }
        for (int e = 0; e < EC; e++) {
            size_t off = (size_t)e * ME * CCH;
            gemm_rv<2, 1, 12><<<ME / 64, 256, 0, stream>>>(
                x1 + off, fc1w_c, n2w_c, n2b_c, fc1b_c,
                h1q, nullptr, nullptr, nullptr, 0, 0, flag);
            gemm_rv<3, 4, 3><<<ME / 64, 256, 0, stream>>>(
                h1q, fc2w_c, nullptr, nullptr, fc2b_c,
                nullptr, x1 + off, nullptr, d_out, off, 0, flag);
        }
    }
}

// Round 6
// 619.173 us; speedup vs baseline: 1.2992x; 1.1460x over previous
//
#include <hip/hip_runtime.h>

#define WS7    7
#define SHIFT3 3
#define NHEAD  6
#define CCH    192
#define HDIM   32
#define HH56   56
#define LTOK   (HH56*HH56)      // 3136
#define NWIN   64
#define NBATCH 32
#define NWTOT  (NBATCH*NWIN)    // 2048
#define LW     49
#define MTOK   (NWTOT*LW)       // 100352

typedef unsigned short u16;
typedef unsigned int   u32;
typedef __bf16 b16;
typedef b16   b16x8 __attribute__((ext_vector_type(8)));
typedef u16   u16x8 __attribute__((ext_vector_type(8)));
typedef float f32x4 __attribute__((ext_vector_type(4)));

__device__ __forceinline__ float b2f(u16 u) {
    u32 x = ((u32)u) << 16;
    return __builtin_bit_cast(float, x);
}
__device__ __forceinline__ u16 f2b(float f) {
    u32 x = __builtin_bit_cast(u32, f);
    u32 r = x + 0x7FFFu + ((x >> 16) & 1u);
    return (u16)(r >> 16);
}
__device__ __forceinline__ float gelu_exact(float x) {
    return 0.5f * x * (1.0f + erff(x * 0.7071067811865475f));
}

// token m (window-order) -> (b, l) image order (bijection)
__device__ __forceinline__ int map_token(int m, int &b) {
    int widx = m / LW, p = m - widx * LW;
    b = widx >> 6;
    int wloc = widx & 63;
    int wh = wloc >> 3, ww = wloc & 7;
    int i = p / WS7, j = p - i * WS7;
    int gh = wh * WS7 + i + SHIFT3; if (gh >= HH56) gh -= HH56;
    int gw = ww * WS7 + j + SHIFT3; if (gw >= HH56) gw -= HH56;
    return gh * HH56 + gw;
}

// ---- dtype probe: flag=1 if x is fp32 storage, 0 if bf16 storage.
__global__ __launch_bounds__(1024) void probe_kernel(const u16* __restrict__ x, int* flag) {
    __shared__ int ch, cz;
    if (threadIdx.x == 0) { ch = 0; cz = 0; }
    __syncthreads();
    int i = threadIdx.x * 16;
    u16x8 a = *(const u16x8*)(x + i);
    u16x8 b = *(const u16x8*)(x + i + 8);
    int h = 0, z = 0;
    #pragma unroll
    for (int q = 0; q < 8; q++) {
        h += (((a[q] >> 7) & 0xFF) >= 0xC0) + (((b[q] >> 7) & 0xFF) >= 0xC0);
        z += (a[q] == 0) + (b[q] == 0);
    }
    #pragma unroll
    for (int off = 32; off > 0; off >>= 1) {
        h += __shfl_xor(h, off, 64);
        z += __shfl_xor(z, off, 64);
    }
    if ((threadIdx.x & 63) == 0) { atomicAdd(&ch, h); atomicAdd(&cz, z); }
    __syncthreads();
    if (threadIdx.x == 0) *flag = (ch > 250 || cz > 2048) ? 1 : 0;
}

// ---- canonicalize ALL param tensors to bf16 in ONE launch.
#define CANON_TOTAL 445302
__global__ __launch_bounds__(256) void canon_all_kernel(
    const int* __restrict__ flag,
    const void* s0, const void* s1, const void* s2,  const void* s3,
    const void* s4, const void* s5, const void* s6,  const void* s7,
    const void* s8, const void* s9, const void* s10, const void* s11,
    char* __restrict__ ws)
{
    int i = blockIdx.x * 256 + threadIdx.x;
    if (i >= CANON_TOTAL) return;
    const void* srcs[12] = {s0, s1, s2, s3, s4, s5, s6, s7, s8, s9, s10, s11};
    const int cnt[12] = {110592, 36864, 147456, 147456, 192, 192, 192, 192, 192, 768, 192, 1014};
    const int off[12] = {64, 221248, 294976, 589888, 884800, 885184, 885568, 885952, 886336, 886720, 888256, 888640};
    int seg = 0, base = 0;
    while (seg < 11 && i >= base + cnt[seg]) { base += cnt[seg]; seg++; }
    int j = i - base;
    const void* sp = srcs[seg];
    u16* dp = (u16*)(ws + off[seg]);
    dp[j] = (*flag) ? f2b(((const float*)sp)[j]) : ((const u16*)sp)[j];
}

// ---- LayerNorm. GATHER=1: src = d_in[0] (dtype per flag), rows via map_token.
template<int GATHER>
__global__ __launch_bounds__(256) void ln_kernel(
    const void* __restrict__ src, const u16* __restrict__ w, const u16* __restrict__ bia,
    u16* __restrict__ dst, int m_base, const int* __restrict__ flag)
{
    int wave = threadIdx.x >> 6, lane = threadIdx.x & 63;
    int mloc = blockIdx.x * 4 + wave;
    size_t row;
    if (GATHER) { int b; int l = map_token(m_base + mloc, b); row = (size_t)b * LTOK + l; }
    else row = mloc;
    float v0, v1, v2;
    if (GATHER && *flag) {
        const float* xp = (const float*)src + row * CCH;
        v0 = xp[lane]; v1 = xp[lane + 64]; v2 = xp[lane + 128];
    } else {
        const u16* xp = (const u16*)src + row * CCH;
        v0 = b2f(xp[lane]); v1 = b2f(xp[lane + 64]); v2 = b2f(xp[lane + 128]);
    }
    float s = v0 + v1 + v2, sq = v0 * v0 + v1 * v1 + v2 * v2;
    for (int off = 32; off > 0; off >>= 1) {
        s  += __shfl_xor(s, off, 64);
        sq += __shfl_xor(sq, off, 64);
    }
    float mean = s * (1.f / 192.f);
    float var  = fmaxf(sq * (1.f / 192.f) - mean * mean, 0.f);
    float rstd = rsqrtf(var + 1e-5f);
    u16* op = dst + (size_t)mloc * CCH;
    op[lane]       = f2b((v0 - mean) * rstd * b2f(w[lane])       + b2f(bia[lane]));
    op[lane + 64]  = f2b((v1 - mean) * rstd * b2f(w[lane + 64])  + b2f(bia[lane + 64]));
    op[lane + 128] = f2b((v2 - mean) * rstd * b2f(w[lane + 128]) + b2f(bia[lane + 128]));
}

// ---- DMA-stage a ROWSx32 bf16 chunk (row stride ldk u16) into LDS [ROWS][40].
// Rows are 80B = 5 chunks of 16B (4 real + 1 pad; pad source clamped to row
// start, data unused). LDS dst linear in chunk id (wave-uniform base rule).
template<int ROWS>
__device__ __forceinline__ void stageT(const u16* __restrict__ g, int ldk, u16* s, int tid) {
    constexpr int CH = ROWS * 5;
    constexpr int ITER = (CH + 255) / 256;
    #pragma unroll
    for (int it = 0; it < ITER; it++) {
        int t = it * 256 + tid;
        if ((CH % 256 == 0) || t < CH) {
            int row = t / 5, c = t - row * 5;
            int cc = (c == 4) ? 0 : c;
            const u16* src = g + (size_t)row * ldk + cc * 8;
            u16* dst = s + (size_t)(it * 256 + (tid & ~63)) * 8;   // wave base
            __builtin_amdgcn_global_load_lds(
                (const __attribute__((address_space(1))) void*)src,
                (__attribute__((address_space(3))) void*)dst, 16, 0, 0);
        }
    }
}

// ---- Uniform GEMM, m97-shaped: block = 128 M x 192 N, BK=32, both operands
// DMA-staged to double-buffered LDS; stage(t+1) issued BEFORE compute(t);
// ONE barrier per K-step covering 96 MFMAs/block; 51.2KB LDS -> 3 blocks/CU.
// 4 waves in 2x2 grid, wave tile 64x96 (acc 4x6 f32x4 = 96 VGPR).
// MODE 0: qkv  C=A*B^T -> Cb (stride 576)
// MODE 1: proj + bias + residual-scatter into X1 (map_token, Xin dtype flag)
// MODE 2: fc1 + bias + gelu -> Cb (stride 768)
// MODE 3: fc2 + bias + gelu + residual(X1) -> Oout (dtype flag)
template<int MODE, int KK>
__global__ __launch_bounds__(256, 3) void gemm_t(
    const u16* __restrict__ A, const u16* __restrict__ Bm,
    const u16* __restrict__ bias,
    u16* __restrict__ Cb, u16* __restrict__ X1, const void* __restrict__ Xin,
    void* __restrict__ Oout, size_t o_off, int m_base,
    const int* __restrict__ flag)
{
    __shared__ __align__(16) u16 As[2][128 * 40];
    __shared__ __align__(16) u16 Bs[2][192 * 40];
    int tid = threadIdx.x;
    int m0 = blockIdx.x * 128, n0 = blockIdx.y * 192;
    int wave = tid >> 6, lane = tid & 63;
    int wm = wave >> 1, wn = wave & 1;
    int quad = lane >> 4, mr = lane & 15;

    const u16* Ag = A + (size_t)m0 * KK;
    const u16* Bg = Bm + (size_t)n0 * KK;

    stageT<128>(Ag, KK, As[0], tid);
    stageT<192>(Bg, KK, Bs[0], tid);
    __syncthreads();

    f32x4 acc[4][6] = {};
    constexpr int NSTEP = KK / 32;

    #pragma unroll 1
    for (int t = 0; t < NSTEP; t++) {
        int cur = t & 1;
        if (t + 1 < NSTEP) {
            stageT<128>(Ag + (t + 1) * 32, KK, As[cur ^ 1], tid);
            stageT<192>(Bg + (t + 1) * 32, KK, Bs[cur ^ 1], tid);
        }
        const u16* pa = &As[cur][(wm * 64 + mr) * 40 + quad * 8];
        const u16* pb = &Bs[cur][(wn * 96 + mr) * 40 + quad * 8];
        b16x8 a[4], b[6];
        #pragma unroll
        for (int sm = 0; sm < 4; sm++)
            a[sm] = __builtin_bit_cast(b16x8, *(const u16x8*)(pa + sm * 16 * 40));
        #pragma unroll
        for (int sn = 0; sn < 6; sn++)
            b[sn] = __builtin_bit_cast(b16x8, *(const u16x8*)(pb + sn * 16 * 40));
        #pragma unroll
        for (int sm = 0; sm < 4; sm++)
            #pragma unroll
            for (int sn = 0; sn < 6; sn++)
                acc[sm][sn] = __builtin_amdgcn_mfma_f32_16x16x32_bf16(a[sm], b[sn], acc[sm][sn], 0, 0, 0);
        __syncthreads();   // drains stage(t+1) DMA (issued a full phase ago)
    }

    int isf = *flag;
    #pragma unroll
    for (int sm = 0; sm < 4; sm++) {
        #pragma unroll
        for (int r = 0; r < 4; r++) {
            int mm = m0 + wm * 64 + sm * 16 + quad * 4 + r;
            int bimg = 0, limg = 0;
            if (MODE == 1) { limg = map_token(m_base + mm, bimg); }
            #pragma unroll
            for (int sn = 0; sn < 6; sn++) {
                float val = acc[sm][sn][r];
                int nn = n0 + wn * 96 + sn * 16 + mr;
                if (MODE == 0) {
                    Cb[(size_t)mm * 576 + nn] = f2b(val);
                } else if (MODE == 1) {
                    val += b2f(bias[nn]);
                    size_t idx = ((size_t)bimg * LTOK + limg) * CCH + nn;
                    float xi = isf ? ((const float*)Xin)[idx] : b2f(((const u16*)Xin)[idx]);
                    X1[idx] = f2b(xi + val);
                } else if (MODE == 2) {
                    val = gelu_exact(val + b2f(bias[nn]));
                    Cb[(size_t)mm * 768 + nn] = f2b(val);
                } else {
                    val = gelu_exact(val + b2f(bias[nn]));
                    size_t idx = (size_t)mm * CCH + nn;
                    float r2 = val + b2f(X1[idx]);
                    if (isf) ((float*)Oout)[o_off + idx] = r2;
                    else     ((u16*)Oout)[o_off + idx]  = f2b(r2);
                }
            }
        }
    }
}

// ---- MFMA attention (unchanged, verified)
__global__ __launch_bounds__(256) void attn_kernel(
    const u16* __restrict__ qkv, const u16* __restrict__ rel_bias,
    u16* __restrict__ aout)
{
    __shared__ __align__(16) u16 qs[64 * 32];
    __shared__ __align__(16) u16 ks[64 * 32];
    __shared__ __align__(16) u16 vsT[32 * 72];
    __shared__ __align__(16) u16 ps[64 * 72];
    __shared__ float bias_s[169];
    int blk = blockIdx.x;
    int widx = blk / NHEAD, head = blk - widx * NHEAD;
    int wloc = widx & 63;
    int wh = wloc >> 3, ww = wloc & 7;
    int tid = threadIdx.x;
    const u16* base = qkv + (size_t)widx * LW * 576 + head * HDIM;

    if (tid < 196) {
        int i = tid >> 2, c8 = (tid & 3) * 8;
        *(uint4*)&qs[i * 32 + c8] = *(const uint4*)(base + (size_t)i * 576 + c8);
        *(uint4*)&ks[i * 32 + c8] = *(const uint4*)(base + (size_t)i * 576 + 192 + c8);
        u16x8 vv = *(const u16x8*)(base + (size_t)i * 576 + 384 + c8);
        #pragma unroll
        for (int q = 0; q < 8; q++) vsT[(c8 + q) * 72 + i] = vv[q];
    }
    for (int idx = tid; idx < 32 * 15; idx += 256) {   // zero pad cols 49..63
        int d = idx / 15, j = 49 + (idx - d * 15);
        vsT[d * 72 + j] = 0;
    }
    if (tid < 169) bias_s[tid] = b2f(rel_bias[tid * NHEAD + head]);
    __syncthreads();

    int wave = tid >> 6, lane = tid & 63;
    int quad = lane >> 4, c = lane & 15;

    b16x8 aq = __builtin_bit_cast(b16x8, *(const u16x8*)&qs[(wave * 16 + c) * 32 + quad * 8]);
    f32x4 sacc[4];
    #pragma unroll
    for (int nt = 0; nt < 4; nt++) {
        b16x8 bk = __builtin_bit_cast(b16x8, *(const u16x8*)&ks[(nt * 16 + c) * 32 + quad * 8]);
        f32x4 z = {};
        sacc[nt] = __builtin_amdgcn_mfma_f32_16x16x32_bf16(aq, bk, z, 0, 0, 0);
    }

    const float SCALE = 13.856406460551018f;
    float val[4][4];
    int rbase = wave * 16 + quad * 4;
    #pragma unroll
    for (int r = 0; r < 4; r++) {
        int i = rbase + r;
        int ih = i / WS7, iw = i - ih * WS7;
        int ri = (wh == 7 ? (ih < 4 ? 1 : 2) : 0) * 3 + (ww == 7 ? (iw < 4 ? 1 : 2) : 0);
        #pragma unroll
        for (int nt = 0; nt < 4; nt++) {
            int j = nt * 16 + c;
            float v;
            if (i >= LW) v = 0.f;
            else if (j >= LW) v = -1e30f;
            else {
                int jh = j / WS7, jw = j - jh * WS7;
                int rj = (wh == 7 ? (jh < 4 ? 1 : 2) : 0) * 3 + (ww == 7 ? (jw < 4 ? 1 : 2) : 0);
                if (ri != rj) v = -100.0f;
                else v = fmaf(sacc[nt][r], SCALE, bias_s[(ih - jh + 6) * 13 + (iw - jw + 6)]);
            }
            val[r][nt] = v;
        }
    }

    #pragma unroll
    for (int r = 0; r < 4; r++) {
        float mx = fmaxf(fmaxf(val[r][0], val[r][1]), fmaxf(val[r][2], val[r][3]));
        for (int d = 1; d < 16; d <<= 1) mx = fmaxf(mx, __shfl_xor(mx, d, 64));
        float sum = 0.f;
        #pragma unroll
        for (int nt = 0; nt < 4; nt++) { float e = expf(val[r][nt] - mx); val[r][nt] = e; sum += e; }
        for (int d = 1; d < 16; d <<= 1) sum += __shfl_xor(sum, d, 64);
        float inv = 1.f / sum;
        int i = rbase + r;
        #pragma unroll
        for (int nt = 0; nt < 4; nt++)
            ps[i * 72 + nt * 16 + c] = f2b(val[r][nt] * inv);
    }

    f32x4 oacc[2] = {{}, {}};
    #pragma unroll
    for (int kh = 0; kh < 2; kh++) {
        b16x8 ap = __builtin_bit_cast(b16x8, *(const u16x8*)&ps[(wave * 16 + c) * 72 + kh * 32 + quad * 8]);
        #pragma unroll
        for (int nt = 0; nt < 2; nt++) {
            b16x8 bv = __builtin_bit_cast(b16x8, *(const u16x8*)&vsT[(nt * 16 + c) * 72 + kh * 32 + quad * 8]);
            oacc[nt] = __builtin_amdgcn_mfma_f32_16x16x32_bf16(ap, bv, oacc[nt], 0, 0, 0);
        }
    }
    #pragma unroll
    for (int nt = 0; nt < 2; nt++) {
        #pragma unroll
        for (int r = 0; r < 4; r++) {
            int i = rbase + r;
            if (i < LW)
                aout[((size_t)widx * LW + i) * CCH + head * HDIM + nt * 16 + c] = f2b(oacc[nt][r]);
        }
    }
}

extern "C" void kernel_launch(void* const* d_in, const int* in_sizes, int n_in,
                              void* d_out, int out_size, void* d_ws, size_t ws_size,
                              hipStream_t stream)
{
    const void* x_in = d_in[0];
    char* ws = (char*)d_ws;
    int* flag = (int*)ws;

    u16* qkvw_c  = (u16*)(ws + 64);
    u16* projw_c = (u16*)(ws + 221248);
    u16* fc1w_c  = (u16*)(ws + 294976);
    u16* fc2w_c  = (u16*)(ws + 589888);
    u16* n1w_c   = (u16*)(ws + 884800);
    u16* n1b_c   = (u16*)(ws + 885184);
    u16* n2w_c   = (u16*)(ws + 885568);
    u16* n2b_c   = (u16*)(ws + 885952);
    u16* projb_c = (u16*)(ws + 886336);
    u16* fc1b_c  = (u16*)(ws + 886720);
    u16* fc2b_c  = (u16*)(ws + 888256);
    u16* relb_c  = (u16*)(ws + 888640);

    const size_t P0 = 1u << 20;
    const size_t X1SZ   = (size_t)MTOK * CCH * 2;   //  38,535,168
    const size_t QKVSZ  = (size_t)MTOK * 576 * 2;   // 115,605,504

    u16* x1 = (u16*)(ws + P0);

    probe_kernel<<<1, 1024, 0, stream>>>((const u16*)x_in, flag);
    canon_all_kernel<<<(CANON_TOTAL + 255) / 256, 256, 0, stream>>>(
        flag,
        d_in[7], d_in[9], d_in[13], d_in[15],
        d_in[5], d_in[6], d_in[11], d_in[12],
        d_in[10], d_in[14], d_in[16], d_in[8],
        ws);

    if (ws_size >= P0 + 3 * X1SZ + QKVSZ) {
        // ---- big tier. Layout: x1 | winq(xn) | aout | qkvq ; h1 aliases aout+qkvq.
        u16* winq = (u16*)(ws + P0 + X1SZ);
        u16* aout = (u16*)(ws + P0 + 2 * X1SZ);
        u16* qkvq = (u16*)(ws + P0 + 3 * X1SZ);
        u16* h1q  = aout;   // 154.1 MB = aout(38.5) + qkvq(115.6), both dead by fc1

        ln_kernel<1><<<MTOK / 4, 256, 0, stream>>>(x_in, n1w_c, n1b_c, winq, 0, flag);
        gemm_t<0, 192><<<dim3(MTOK / 128, 3), 256, 0, stream>>>(
            winq, qkvw_c, nullptr, qkvq, nullptr, nullptr, nullptr, 0, 0, flag);
        attn_kernel<<<NWTOT * NHEAD, 256, 0, stream>>>(qkvq, relb_c, aout);
        gemm_t<1, 192><<<dim3(MTOK / 128, 1), 256, 0, stream>>>(
            aout, projw_c, projb_c, nullptr, x1, x_in, nullptr, 0, 0, flag);
        ln_kernel<0><<<MTOK / 4, 256, 0, stream>>>(x1, n2w_c, n2b_c, winq, 0, flag);
        gemm_t<2, 192><<<dim3(MTOK / 128, 4), 256, 0, stream>>>(
            winq, fc1w_c, fc1b_c, h1q, nullptr, nullptr, nullptr, 0, 0, flag);
        gemm_t<3, 768><<<dim3(MTOK / 128, 1), 256, 0, stream>>>(
            h1q, fc2w_c, fc2b_c, nullptr, x1, nullptr, d_out, 0, 0, flag);
    } else {
        // ---- small tier (<=78 MB scratch): 8-way chunked both phases.
        const int QC = 8, EC = 8;
        const int MQ = MTOK / QC, ME = MTOK / EC;    // 12544 = 98*128
        u16* winq = (u16*)(ws + P0 + X1SZ);                       // 4.8 MB
        u16* aout = (u16*)(ws + P0 + X1SZ + (size_t)MQ * CCH * 2);
        u16* qkvq = (u16*)(ws + P0 + X1SZ + 2 * (size_t)MQ * CCH * 2);
        u16* h1q  = winq;    // 19.3 MB aliases winq+aout+qkvq region in MLP phase

        for (int q = 0; q < QC; q++) {
            int mb = q * MQ;
            ln_kernel<1><<<MQ / 4, 256, 0, stream>>>(x_in, n1w_c, n1b_c, winq, mb, flag);
            gemm_t<0, 192><<<dim3(MQ / 128, 3), 256, 0, stream>>>(
                winq, qkvw_c, nullptr, qkvq, nullptr, nullptr, nullptr, 0, mb, flag);
            attn_kernel<<<(NWTOT / QC) * NHEAD, 256, 0, stream>>>(qkvq, relb_c, aout);
            gemm_t<1, 192><<<dim3(MQ / 128, 1), 256, 0, stream>>>(
                aout, projw_c, projb_c, nullptr, x1, x_in, nullptr, 0, mb, flag);
        }
        u16* xnq = (u16*)(ws + P0 + X1SZ + (size_t)ME * 768 * 2);  // after h1
        for (int e = 0; e < EC; e++) {
            size_t off = (size_t)e * ME * CCH;
            ln_kernel<0><<<ME / 4, 256, 0, stream>>>(x1 + off, n2w_c, n2b_c, xnq, 0, flag);
            gemm_t<2, 192><<<dim3(ME / 128, 4), 256, 0, stream>>>(
                xnq, fc1w_c, fc1b_c, h1q, nullptr, nullptr, nullptr, 0, 0, flag);
            gemm_t<3, 768><<<dim3(ME / 128, 1), 256, 0, stream>>>(
                h1q, fc2w_c, fc2b_c, nullptr, x1 + off, nullptr, d_out, off, 0, flag);
        }
    }
}

// Round 7
// 606.943 us; speedup vs baseline: 1.3254x; 1.0201x over previous
//
#include <hip/hip_runtime.h>

#define WS7    7
#define SHIFT3 3
#define NHEAD  6
#define CCH    192
#define HDIM   32
#define HH56   56
#define LTOK   (HH56*HH56)      // 3136
#define NWIN   64
#define NBATCH 32
#define NWTOT  (NBATCH*NWIN)    // 2048
#define LW     49
#define MTOK   (NWTOT*LW)       // 100352

typedef unsigned short u16;
typedef unsigned int   u32;
typedef __bf16 b16;
typedef b16   b16x8 __attribute__((ext_vector_type(8)));
typedef u16   u16x8 __attribute__((ext_vector_type(8)));
typedef float f32x4 __attribute__((ext_vector_type(4)));

__device__ __forceinline__ float b2f(u16 u) {
    u32 x = ((u32)u) << 16;
    return __builtin_bit_cast(float, x);
}
__device__ __forceinline__ u16 f2b(float f) {
    u32 x = __builtin_bit_cast(u32, f);
    u32 r = x + 0x7FFFu + ((x >> 16) & 1u);
    return (u16)(r >> 16);
}
__device__ __forceinline__ float gelu_exact(float x) {
    return 0.5f * x * (1.0f + erff(x * 0.7071067811865475f));
}

// token m (window-order) -> (b, l) image order (bijection)
__device__ __forceinline__ int map_token(int m, int &b) {
    int widx = m / LW, p = m - widx * LW;
    b = widx >> 6;
    int wloc = widx & 63;
    int wh = wloc >> 3, ww = wloc & 7;
    int i = p / WS7, j = p - i * WS7;
    int gh = wh * WS7 + i + SHIFT3; if (gh >= HH56) gh -= HH56;
    int gw = ww * WS7 + j + SHIFT3; if (gw >= HH56) gw -= HH56;
    return gh * HH56 + gw;
}

// ---- dtype probe: flag=1 if x is fp32 storage, 0 if bf16 storage.
__global__ __launch_bounds__(1024) void probe_kernel(const u16* __restrict__ x, int* flag) {
    __shared__ int ch, cz;
    if (threadIdx.x == 0) { ch = 0; cz = 0; }
    __syncthreads();
    int i = threadIdx.x * 16;
    u16x8 a = *(const u16x8*)(x + i);
    u16x8 b = *(const u16x8*)(x + i + 8);
    int h = 0, z = 0;
    #pragma unroll
    for (int q = 0; q < 8; q++) {
        h += (((a[q] >> 7) & 0xFF) >= 0xC0) + (((b[q] >> 7) & 0xFF) >= 0xC0);
        z += (a[q] == 0) + (b[q] == 0);
    }
    #pragma unroll
    for (int off = 32; off > 0; off >>= 1) {
        h += __shfl_xor(h, off, 64);
        z += __shfl_xor(z, off, 64);
    }
    if ((threadIdx.x & 63) == 0) { atomicAdd(&ch, h); atomicAdd(&cz, z); }
    __syncthreads();
    if (threadIdx.x == 0) *flag = (ch > 250 || cz > 2048) ? 1 : 0;
}

// ---- canonicalize ALL param tensors to bf16 in ONE launch.
#define CANON_TOTAL 445302
__global__ __launch_bounds__(256) void canon_all_kernel(
    const int* __restrict__ flag,
    const void* s0, const void* s1, const void* s2,  const void* s3,
    const void* s4, const void* s5, const void* s6,  const void* s7,
    const void* s8, const void* s9, const void* s10, const void* s11,
    char* __restrict__ ws)
{
    int i = blockIdx.x * 256 + threadIdx.x;
    if (i >= CANON_TOTAL) return;
    const void* srcs[12] = {s0, s1, s2, s3, s4, s5, s6, s7, s8, s9, s10, s11};
    const int cnt[12] = {110592, 36864, 147456, 147456, 192, 192, 192, 192, 192, 768, 192, 1014};
    const int off[12] = {64, 221248, 294976, 589888, 884800, 885184, 885568, 885952, 886336, 886720, 888256, 888640};
    int seg = 0, base = 0;
    while (seg < 11 && i >= base + cnt[seg]) { base += cnt[seg]; seg++; }
    int j = i - base;
    const void* sp = srcs[seg];
    u16* dp = (u16*)(ws + off[seg]);
    dp[j] = (*flag) ? f2b(((const float*)sp)[j]) : ((const u16*)sp)[j];
}

// ---- LayerNorm. GATHER=1: src = d_in[0] (dtype per flag), rows via map_token.
template<int GATHER>
__global__ __launch_bounds__(256) void ln_kernel(
    const void* __restrict__ src, const u16* __restrict__ w, const u16* __restrict__ bia,
    u16* __restrict__ dst, int m_base, const int* __restrict__ flag)
{
    int wave = threadIdx.x >> 6, lane = threadIdx.x & 63;
    int mloc = blockIdx.x * 4 + wave;
    size_t row;
    if (GATHER) { int b; int l = map_token(m_base + mloc, b); row = (size_t)b * LTOK + l; }
    else row = mloc;
    float v0, v1, v2;
    if (GATHER && *flag) {
        const float* xp = (const float*)src + row * CCH;
        v0 = xp[lane]; v1 = xp[lane + 64]; v2 = xp[lane + 128];
    } else {
        const u16* xp = (const u16*)src + row * CCH;
        v0 = b2f(xp[lane]); v1 = b2f(xp[lane + 64]); v2 = b2f(xp[lane + 128]);
    }
    float s = v0 + v1 + v2, sq = v0 * v0 + v1 * v1 + v2 * v2;
    for (int off = 32; off > 0; off >>= 1) {
        s  += __shfl_xor(s, off, 64);
        sq += __shfl_xor(sq, off, 64);
    }
    float mean = s * (1.f / 192.f);
    float var  = fmaxf(sq * (1.f / 192.f) - mean * mean, 0.f);
    float rstd = rsqrtf(var + 1e-5f);
    u16* op = dst + (size_t)mloc * CCH;
    op[lane]       = f2b((v0 - mean) * rstd * b2f(w[lane])       + b2f(bia[lane]));
    op[lane + 64]  = f2b((v1 - mean) * rstd * b2f(w[lane + 64])  + b2f(bia[lane + 64]));
    op[lane + 128] = f2b((v2 - mean) * rstd * b2f(w[lane + 128]) + b2f(bia[lane + 128]));
}

// ---- DMA-stage a ROWSx32 bf16 chunk (row stride ldk u16) into LINEAR LDS
// [ROWS][32] with T2-style chunk swizzle: within each 64B row (4x16B chunks),
// lds chunk c holds global chunk c ^ ((row>>1)&3). Pre-swizzled on the GLOBAL
// source (rule #21: gload_lds dest must be linear); read side applies the same
// XOR. Uniform: EXACTLY ROWS*4/256 loads per thread (A:2, B:3) -> exact
// counted vmcnt.
template<int ROWS>
__device__ __forceinline__ void stageL(const u16* __restrict__ g, int ldk, u16* s, int tid) {
    constexpr int ITER = ROWS * 4 / 256;
    #pragma unroll
    for (int it = 0; it < ITER; it++) {
        int t = it * 256 + tid;
        int row = t >> 2, c = t & 3;
        int cc = c ^ ((row >> 1) & 3);
        const u16* src = g + (size_t)row * ldk + cc * 8;
        u16* dst = s + (size_t)(it * 256 + (tid & ~63)) * 8;   // wave base
        __builtin_amdgcn_global_load_lds(
            (const __attribute__((address_space(1))) void*)src,
            (__attribute__((address_space(3))) void*)dst, 16, 0, 0);
    }
}

// ---- Uniform GEMM with T4 counted-vmcnt pipeline: block = 128M x 192N, BK=32.
// Per K-step: stage(t+1) [5 loads/thread] -> s_waitcnt vmcnt(5) (stage(t)
// landed; stage(t+1) stays IN FLIGHT across the barrier) -> s_barrier ->
// ds_read frags + 96 MFMA -> s_barrier. vmcnt never drains to 0 in the loop.
// LDS 40.6KB -> 3 blocks/CU. 4 waves 2x2, wave tile 64x96.
// MODE 0: qkv -> Cb (stride 576). MODE 1: proj+bias+residual scatter -> X1.
// MODE 2: fc1+bias+gelu -> Cb (stride 768). MODE 3: fc2+bias+gelu+res -> Oout.
template<int MODE, int KK>
__global__ __launch_bounds__(256, 3) void gemm_t(
    const u16* __restrict__ A, const u16* __restrict__ Bm,
    const u16* __restrict__ bias,
    u16* __restrict__ Cb, u16* __restrict__ X1, const void* __restrict__ Xin,
    void* __restrict__ Oout, size_t o_off, int m_base,
    const int* __restrict__ flag)
{
    __shared__ __align__(16) u16 As[2][128 * 32];
    __shared__ __align__(16) u16 Bs[2][192 * 32];
    int tid = threadIdx.x;
    int m0 = blockIdx.x * 128, n0 = blockIdx.y * 192;
    int wave = tid >> 6, lane = tid & 63;
    int wm = wave >> 1, wn = wave & 1;
    int quad = lane >> 4, mr = lane & 15;

    const u16* Ag = A + (size_t)m0 * KK;
    const u16* Bg = Bm + (size_t)n0 * KK;

    stageL<128>(Ag, KK, As[0], tid);
    stageL<192>(Bg, KK, Bs[0], tid);

    f32x4 acc[4][6] = {};
    constexpr int NSTEP = KK / 32;

    #pragma unroll 1
    for (int t = 0; t < NSTEP; t++) {
        int cur = t & 1;
        if (t + 1 < NSTEP) {
            stageL<128>(Ag + (t + 1) * 32, KK, As[cur ^ 1], tid);
            stageL<192>(Bg + (t + 1) * 32, KK, Bs[cur ^ 1], tid);
            asm volatile("s_waitcnt vmcnt(5)");   // stage(t) landed; 5 in flight
        } else {
            asm volatile("s_waitcnt vmcnt(0)");   // last step: full drain
        }
        __builtin_amdgcn_s_barrier();
        __builtin_amdgcn_sched_barrier(0);
        b16x8 a[4], b[6];
        #pragma unroll
        for (int sm = 0; sm < 4; sm++) {
            int row = wm * 64 + sm * 16 + mr;
            a[sm] = __builtin_bit_cast(b16x8,
                *(const u16x8*)&As[cur][row * 32 + (quad ^ ((row >> 1) & 3)) * 8]);
        }
        #pragma unroll
        for (int sn = 0; sn < 6; sn++) {
            int row = wn * 96 + sn * 16 + mr;
            b[sn] = __builtin_bit_cast(b16x8,
                *(const u16x8*)&Bs[cur][row * 32 + (quad ^ ((row >> 1) & 3)) * 8]);
        }
        #pragma unroll
        for (int sm = 0; sm < 4; sm++)
            #pragma unroll
            for (int sn = 0; sn < 6; sn++)
                acc[sm][sn] = __builtin_amdgcn_mfma_f32_16x16x32_bf16(a[sm], b[sn], acc[sm][sn], 0, 0, 0);
        __builtin_amdgcn_sched_barrier(0);
        __builtin_amdgcn_s_barrier();             // protect buf before re-stage
    }

    int isf = *flag;
    #pragma unroll
    for (int sm = 0; sm < 4; sm++) {
        #pragma unroll
        for (int r = 0; r < 4; r++) {
            int mm = m0 + wm * 64 + sm * 16 + quad * 4 + r;
            int bimg = 0, limg = 0;
            if (MODE == 1) { limg = map_token(m_base + mm, bimg); }
            #pragma unroll
            for (int sn = 0; sn < 6; sn++) {
                float val = acc[sm][sn][r];
                int nn = n0 + wn * 96 + sn * 16 + mr;
                if (MODE == 0) {
                    Cb[(size_t)mm * 576 + nn] = f2b(val);
                } else if (MODE == 1) {
                    val += b2f(bias[nn]);
                    size_t idx = ((size_t)bimg * LTOK + limg) * CCH + nn;
                    float xi = isf ? ((const float*)Xin)[idx] : b2f(((const u16*)Xin)[idx]);
                    X1[idx] = f2b(xi + val);
                } else if (MODE == 2) {
                    val = gelu_exact(val + b2f(bias[nn]));
                    Cb[(size_t)mm * 768 + nn] = f2b(val);
                } else {
                    val = gelu_exact(val + b2f(bias[nn]));
                    size_t idx = (size_t)mm * CCH + nn;
                    float r2 = val + b2f(X1[idx]);
                    if (isf) ((float*)Oout)[o_off + idx] = r2;
                    else     ((u16*)Oout)[o_off + idx]  = f2b(r2);
                }
            }
        }
    }
}

// ---- MFMA attention (unchanged, verified)
__global__ __launch_bounds__(256) void attn_kernel(
    const u16* __restrict__ qkv, const u16* __restrict__ rel_bias,
    u16* __restrict__ aout)
{
    __shared__ __align__(16) u16 qs[64 * 32];
    __shared__ __align__(16) u16 ks[64 * 32];
    __shared__ __align__(16) u16 vsT[32 * 72];
    __shared__ __align__(16) u16 ps[64 * 72];
    __shared__ float bias_s[169];
    int blk = blockIdx.x;
    int widx = blk / NHEAD, head = blk - widx * NHEAD;
    int wloc = widx & 63;
    int wh = wloc >> 3, ww = wloc & 7;
    int tid = threadIdx.x;
    const u16* base = qkv + (size_t)widx * LW * 576 + head * HDIM;

    if (tid < 196) {
        int i = tid >> 2, c8 = (tid & 3) * 8;
        *(uint4*)&qs[i * 32 + c8] = *(const uint4*)(base + (size_t)i * 576 + c8);
        *(uint4*)&ks[i * 32 + c8] = *(const uint4*)(base + (size_t)i * 576 + 192 + c8);
        u16x8 vv = *(const u16x8*)(base + (size_t)i * 576 + 384 + c8);
        #pragma unroll
        for (int q = 0; q < 8; q++) vsT[(c8 + q) * 72 + i] = vv[q];
    }
    for (int idx = tid; idx < 32 * 15; idx += 256) {   // zero pad cols 49..63
        int d = idx / 15, j = 49 + (idx - d * 15);
        vsT[d * 72 + j] = 0;
    }
    if (tid < 169) bias_s[tid] = b2f(rel_bias[tid * NHEAD + head]);
    __syncthreads();

    int wave = tid >> 6, lane = tid & 63;
    int quad = lane >> 4, c = lane & 15;

    b16x8 aq = __builtin_bit_cast(b16x8, *(const u16x8*)&qs[(wave * 16 + c) * 32 + quad * 8]);
    f32x4 sacc[4];
    #pragma unroll
    for (int nt = 0; nt < 4; nt++) {
        b16x8 bk = __builtin_bit_cast(b16x8, *(const u16x8*)&ks[(nt * 16 + c) * 32 + quad * 8]);
        f32x4 z = {};
        sacc[nt] = __builtin_amdgcn_mfma_f32_16x16x32_bf16(aq, bk, z, 0, 0, 0);
    }

    const float SCALE = 13.856406460551018f;
    float val[4][4];
    int rbase = wave * 16 + quad * 4;
    #pragma unroll
    for (int r = 0; r < 4; r++) {
        int i = rbase + r;
        int ih = i / WS7, iw = i - ih * WS7;
        int ri = (wh == 7 ? (ih < 4 ? 1 : 2) : 0) * 3 + (ww == 7 ? (iw < 4 ? 1 : 2) : 0);
        #pragma unroll
        for (int nt = 0; nt < 4; nt++) {
            int j = nt * 16 + c;
            float v;
            if (i >= LW) v = 0.f;
            else if (j >= LW) v = -1e30f;
            else {
                int jh = j / WS7, jw = j - jh * WS7;
                int rj = (wh == 7 ? (jh < 4 ? 1 : 2) : 0) * 3 + (ww == 7 ? (jw < 4 ? 1 : 2) : 0);
                if (ri != rj) v = -100.0f;
                else v = fmaf(sacc[nt][r], SCALE, bias_s[(ih - jh + 6) * 13 + (iw - jw + 6)]);
            }
            val[r][nt] = v;
        }
    }

    #pragma unroll
    for (int r = 0; r < 4; r++) {
        float mx = fmaxf(fmaxf(val[r][0], val[r][1]), fmaxf(val[r][2], val[r][3]));
        for (int d = 1; d < 16; d <<= 1) mx = fmaxf(mx, __shfl_xor(mx, d, 64));
        float sum = 0.f;
        #pragma unroll
        for (int nt = 0; nt < 4; nt++) { float e = expf(val[r][nt] - mx); val[r][nt] = e; sum += e; }
        for (int d = 1; d < 16; d <<= 1) sum += __shfl_xor(sum, d, 64);
        float inv = 1.f / sum;
        int i = rbase + r;
        #pragma unroll
        for (int nt = 0; nt < 4; nt++)
            ps[i * 72 + nt * 16 + c] = f2b(val[r][nt] * inv);
    }

    f32x4 oacc[2] = {{}, {}};
    #pragma unroll
    for (int kh = 0; kh < 2; kh++) {
        b16x8 ap = __builtin_bit_cast(b16x8, *(const u16x8*)&ps[(wave * 16 + c) * 72 + kh * 32 + quad * 8]);
        #pragma unroll
        for (int nt = 0; nt < 2; nt++) {
            b16x8 bv = __builtin_bit_cast(b16x8, *(const u16x8*)&vsT[(nt * 16 + c) * 72 + kh * 32 + quad * 8]);
            oacc[nt] = __builtin_amdgcn_mfma_f32_16x16x32_bf16(ap, bv, oacc[nt], 0, 0, 0);
        }
    }
    #pragma unroll
    for (int nt = 0; nt < 2; nt++) {
        #pragma unroll
        for (int r = 0; r < 4; r++) {
            int i = rbase + r;
            if (i < LW)
                aout[((size_t)widx * LW + i) * CCH + head * HDIM + nt * 16 + c] = f2b(oacc[nt][r]);
        }
    }
}

extern "C" void kernel_launch(void* const* d_in, const int* in_sizes, int n_in,
                              void* d_out, int out_size, void* d_ws, size_t ws_size,
                              hipStream_t stream)
{
    const void* x_in = d_in[0];
    char* ws = (char*)d_ws;
    int* flag = (int*)ws;

    u16* qkvw_c  = (u16*)(ws + 64);
    u16* projw_c = (u16*)(ws + 221248);
    u16* fc1w_c  = (u16*)(ws + 294976);
    u16* fc2w_c  = (u16*)(ws + 589888);
    u16* n1w_c   = (u16*)(ws + 884800);
    u16* n1b_c   = (u16*)(ws + 885184);
    u16* n2w_c   = (u16*)(ws + 885568);
    u16* n2b_c   = (u16*)(ws + 885952);
    u16* projb_c = (u16*)(ws + 886336);
    u16* fc1b_c  = (u16*)(ws + 886720);
    u16* fc2b_c  = (u16*)(ws + 888256);
    u16* relb_c  = (u16*)(ws + 888640);

    const size_t P0 = 1u << 20;
    const size_t X1SZ   = (size_t)MTOK * CCH * 2;   //  38,535,168
    const size_t QKVSZ  = (size_t)MTOK * 576 * 2;   // 115,605,504

    u16* x1 = (u16*)(ws + P0);

    probe_kernel<<<1, 1024, 0, stream>>>((const u16*)x_in, flag);
    canon_all_kernel<<<(CANON_TOTAL + 255) / 256, 256, 0, stream>>>(
        flag,
        d_in[7], d_in[9], d_in[13], d_in[15],
        d_in[5], d_in[6], d_in[11], d_in[12],
        d_in[10], d_in[14], d_in[16], d_in[8],
        ws);

    if (ws_size >= P0 + 3 * X1SZ + QKVSZ) {
        // ---- big tier. Layout: x1 | winq(xn) | aout | qkvq ; h1 aliases aout+qkvq.
        u16* winq = (u16*)(ws + P0 + X1SZ);
        u16* aout = (u16*)(ws + P0 + 2 * X1SZ);
        u16* qkvq = (u16*)(ws + P0 + 3 * X1SZ);
        u16* h1q  = aout;   // 154.1 MB = aout(38.5) + qkvq(115.6), both dead by fc1

        ln_kernel<1><<<MTOK / 4, 256, 0, stream>>>(x_in, n1w_c, n1b_c, winq, 0, flag);
        gemm_t<0, 192><<<dim3(MTOK / 128, 3), 256, 0, stream>>>(
            winq, qkvw_c, nullptr, qkvq, nullptr, nullptr, nullptr, 0, 0, flag);
        attn_kernel<<<NWTOT * NHEAD, 256, 0, stream>>>(qkvq, relb_c, aout);
        gemm_t<1, 192><<<dim3(MTOK / 128, 1), 256, 0, stream>>>(
            aout, projw_c, projb_c, nullptr, x1, x_in, nullptr, 0, 0, flag);
        ln_kernel<0><<<MTOK / 4, 256, 0, stream>>>(x1, n2w_c, n2b_c, winq, 0, flag);
        gemm_t<2, 192><<<dim3(MTOK / 128, 4), 256, 0, stream>>>(
            winq, fc1w_c, fc1b_c, h1q, nullptr, nullptr, nullptr, 0, 0, flag);
        gemm_t<3, 768><<<dim3(MTOK / 128, 1), 256, 0, stream>>>(
            h1q, fc2w_c, fc2b_c, nullptr, x1, nullptr, d_out, 0, 0, flag);
    } else {
        // ---- small tier (<=78 MB scratch): 8-way chunked both phases.
        const int QC = 8, EC = 8;
        const int MQ = MTOK / QC, ME = MTOK / EC;    // 12544 = 98*128
        u16* winq = (u16*)(ws + P0 + X1SZ);                       // 4.8 MB
        u16* aout = (u16*)(ws + P0 + X1SZ + (size_t)MQ * CCH * 2);
        u16* qkvq = (u16*)(ws + P0 + X1SZ + 2 * (size_t)MQ * CCH * 2);
        u16* h1q  = winq;    // 19.3 MB aliases winq+aout+qkvq region in MLP phase

        for (int q = 0; q < QC; q++) {
            int mb = q * MQ;
            ln_kernel<1><<<MQ / 4, 256, 0, stream>>>(x_in, n1w_c, n1b_c, winq, mb, flag);
            gemm_t<0, 192><<<dim3(MQ / 128, 3), 256, 0, stream>>>(
                winq, qkvw_c, nullptr, qkvq, nullptr, nullptr, nullptr, 0, mb, flag);
            attn_kernel<<<(NWTOT / QC) * NHEAD, 256, 0, stream>>>(qkvq, relb_c, aout);
            gemm_t<1, 192><<<dim3(MQ / 128, 1), 256, 0, stream>>>(
                aout, projw_c, projb_c, nullptr, x1, x_in, nullptr, 0, mb, flag);
        }
        u16* xnq = (u16*)(ws + P0 + X1SZ + (size_t)ME * 768 * 2);  // after h1
        for (int e = 0; e < EC; e++) {
            size_t off = (size_t)e * ME * CCH;
            ln_kernel<0><<<ME / 4, 256, 0, stream>>>(x1 + off, n2w_c, n2b_c, xnq, 0, flag);
            gemm_t<2, 192><<<dim3(ME / 128, 4), 256, 0, stream>>>(
                xnq, fc1w_c, fc1b_c, h1q, nullptr, nullptr, nullptr, 0, 0, flag);
            gemm_t<3, 768><<<dim3(ME / 128, 1), 256, 0, stream>>>(
                h1q, fc2w_c, fc2b_c, nullptr, x1 + off, nullptr, d_out, off, 0, flag);
        }
    }
}